// Round 6
// baseline (4570.139 us; speedup 1.0000x reference)
//
#include <hip/hip_runtime.h>

#define IDX_BITS 20
#define IDX_MASK ((1u << IDX_BITS) - 1)
#define DEADF (1 << 30)           // frontier entry: dead-propagation job
#define CLAIM_SENT (-(1 << 30))   // claimed sentinel; <=96 further decs never wrap
#define NT 1024
#define NB_INIT 256
#define TB2 16                    // tier-2 spin blocks (r9: >16 regress)
#define T2 1536                   // tier-2 while frontier > T2; below: tier-3
#define MAX_ROUNDS 8000
#define SC_CAP 1024
#define SV_CAP 4096

typedef unsigned long long u64;

// All edges are intra-segment, so the per-edge comparison key drops seg:
// key = (~float_bits(hier) << 20) | v ; smaller = earlier in processing order.
__device__ __forceinline__ u64 pack_key(float h, int v) {
  return ((u64)(~__float_as_uint(h)) << IDX_BITS) | (unsigned)v;
}

// R2 coherence scheme (proven): all mutable cross-block data accessed ONLY via
// relaxed agent-scope atomics (bypass L1 + per-XCD L2; served at the IF).
// __syncthreads()/xbar-entry drains vmcnt so stores are at IF before barrier
// counters bump. No fences -> no L2 writeback/invalidate walks; read-only
// neighs/hier stay hot in caches.
__device__ __forceinline__ int ald(const int* p) {
  return __hip_atomic_load((int*)p, __ATOMIC_RELAXED, __HIP_MEMORY_SCOPE_AGENT);
}
__device__ __forceinline__ void ast(int* p, int v) {
  __hip_atomic_store(p, v, __ATOMIC_RELAXED, __HIP_MEMORY_SCOPE_AGENT);
}

// Dataflow algorithm (Kahn layers, synchronous rounds):
//   nsmall[u] = # smaller in-neighbours (k_init, atomicAdd scatter).
//   CENTRE v: atomicExch(nsmall[w], CLAIM) on larger out-nbrs = its kills
//             (centres never decrement) + inert atomicMin grabs on assign.
//   DEAD v:   atomicAdd(nsmall[w], -1); last decrement (old==1) + CAS(0->CLAIM)
//             claims w as a CENTRE (all smaller in-nbrs died).
//   Claim is unique (single atomic wins) => every vertex enters the frontier
//   exactly once; each edge is processed once total, not once per round.
// cnt[] slots: [0..1] round claim counters (parity); [4] nC; [5] an handoff;
// [6] round handoff; [8+s] per-seg centre counts; [32] tier-2 xbar counter.
struct Ctx {
  const int* __restrict__ neighs;
  const float* __restrict__ hier;
  const int* __restrict__ row_splits;
  int V, K, nseg;
  u64* assign;       // [V] min grabber key; ~0 alive; == own key -> centre
  int* nsmall;       // [V] dependency counters / claim state
  int* listA;        // [V] frontier ping
  int* listB;        // [V] frontier pong
  u64* centre_key;   // [V]
  int* centre_v;     // [V]
  int* rank_of;      // [V]
  int* cnt;
  int* out_sel;
  int* out_rs;
  int* out_gg;
};

struct BlkState {
  int sc_cnt, sv_cnt, sc_base, sv_base;
  int seg_hist[8];
  int sc_list[SC_CAP];
  int sv_list[SV_CAP];
};

// Monotonic arrive-counter barrier, no fences (R2 form, proven).
__device__ __forceinline__ void xbar(int* bar, int target) {
  __syncthreads();
  if (threadIdx.x == 0) {
    __hip_atomic_fetch_add(bar, 1, __ATOMIC_RELAXED, __HIP_MEMORY_SCOPE_AGENT);
    while (__hip_atomic_load(bar, __ATOMIC_RELAXED, __HIP_MEMORY_SCOPE_AGENT) < target)
      __builtin_amdgcn_s_sleep(2);
  }
  __syncthreads();
}

__device__ __forceinline__ void record_direct(const Ctx& c, int v, u64 pv) {
  int slot = atomicAdd(&c.cnt[4], 1);
  int seg = 0;
  for (int t = 1; t < c.nseg; ++t) seg += (v >= c.row_splits[t]);
  c.centre_v[slot] = v;
  c.centre_key[slot] = ((u64)seg << 52) | pv;
  atomicAdd(&c.cnt[8 + seg], 1);
}

__device__ __forceinline__ void push_succ(const Ctx& c, BlkState& bs, int* wl,
                                          int* survc, int enc) {
  int s = atomicAdd(&bs.sv_cnt, 1);
  if (s < SV_CAP) bs.sv_list[s] = enc;
  else { int g = atomicAdd(survc, 1); ast(&wl[g], enc); }
}

// Process one frontier round: each entry is a freshly-claimed vertex.
// Quarter-wave (16 lanes) per entry for coalesced 64B row reads.
__device__ void prop_pass(const Ctx& c, BlkState& bs, const int* rl, int* wl,
                          int* survc, int an, int qs, int qst, int ql) {
  for (int i = qs; i < an; i += qst) {
    int e = ald(&rl[i]);
    int v = e & IDX_MASK;
    bool dead = (e & DEADF) != 0;
    u64 pu = pack_key(c.hier[v], v);
    if (c.K == 96) {
      const int* row = c.neighs + (size_t)v * 96;
      int w[6]; u64 kw[6];
#pragma unroll
      for (int t = 0; t < 6; ++t) w[t] = row[ql + 16 * t];
#pragma unroll
      for (int t = 0; t < 6; ++t) kw[t] = pack_key(c.hier[w[t]], w[t]);
      if (!dead) {
#pragma unroll
        for (int t = 0; t < 6; ++t) atomicMin(&c.assign[w[t]], pu);  // inert junk ok
#pragma unroll
        for (int t = 0; t < 6; ++t)
          if (kw[t] > pu) {
            int old = atomicExch(&c.nsmall[w[t]], CLAIM_SENT);
            if (old >= 0) push_succ(c, bs, wl, survc, w[t] | DEADF); // newly dead
          }
        if (ql == 0) {
          int s = atomicAdd(&bs.sc_cnt, 1);
          if (s < SC_CAP) bs.sc_list[s] = v; else record_direct(c, v, pu);
        }
      } else {
#pragma unroll
        for (int t = 0; t < 6; ++t)
          if (kw[t] > pu) {
            int old = atomicAdd(&c.nsmall[w[t]], -1);
            if (old == 1 && atomicCAS(&c.nsmall[w[t]], 0, CLAIM_SENT) == 0)
              push_succ(c, bs, wl, survc, w[t]);                     // newly centre
          }
      }
    } else {
      const int* row = c.neighs + (size_t)v * c.K;
      if (!dead) {
        for (int j = ql; j < c.K; j += 16) atomicMin(&c.assign[row[j]], pu);
        for (int j = ql; j < c.K; j += 16) {
          int w = row[j];
          if (pack_key(c.hier[w], w) > pu) {
            int old = atomicExch(&c.nsmall[w], CLAIM_SENT);
            if (old >= 0) push_succ(c, bs, wl, survc, w | DEADF);
          }
        }
        if (ql == 0) {
          int s = atomicAdd(&bs.sc_cnt, 1);
          if (s < SC_CAP) bs.sc_list[s] = v; else record_direct(c, v, pu);
        }
      } else {
        for (int j = ql; j < c.K; j += 16) {
          int w = row[j];
          if (pack_key(c.hier[w], w) > pu) {
            int old = atomicAdd(&c.nsmall[w], -1);
            if (old == 1 && atomicCAS(&c.nsmall[w], 0, CLAIM_SENT) == 0)
              push_succ(c, bs, wl, survc, w);
          }
        }
      }
    }
  }
}

// Block-aggregated flush: centres -> centre_v/centre_key + seg histogram
// (one cnt[4] add per block per round); survivors -> frontier list.
__device__ __forceinline__ void flush_block(const Ctx& c, BlkState& bs, int* wl, int* survc) {
  __syncthreads();
  int nsc = min(bs.sc_cnt, SC_CAP), nsv = min(bs.sv_cnt, SV_CAP);
  if (threadIdx.x == 0 && nsc) bs.sc_base = atomicAdd(&c.cnt[4], nsc);
  if (threadIdx.x == 0 && nsv) bs.sv_base = atomicAdd(survc, nsv);
  if (threadIdx.x < 8) bs.seg_hist[threadIdx.x] = 0;
  __syncthreads();
  for (int i = threadIdx.x; i < nsv; i += blockDim.x) ast(&wl[bs.sv_base + i], bs.sv_list[i]);
  for (int i = threadIdx.x; i < nsc; i += blockDim.x) {
    int v = bs.sc_list[i];
    int seg = 0;
    for (int t = 1; t < c.nseg; ++t) seg += (v >= c.row_splits[t]);
    c.centre_v[bs.sc_base + i] = v;
    c.centre_key[bs.sc_base + i] = ((u64)seg << 52) | pack_key(c.hier[v], v);
    atomicAdd(&bs.seg_hist[seg], 1);
  }
  __syncthreads();
  if (threadIdx.x < c.nseg) {
    int h = bs.seg_hist[threadIdx.x];
    if (h) atomicAdd(&c.cnt[8 + threadIdx.x], h);
  }
  __syncthreads();
  if (threadIdx.x == 0) { bs.sc_cnt = 0; bs.sv_cnt = 0; }
}

// ============ K0: dependency-counter init ============
__global__ void __launch_bounds__(NT) k_init(Ctx c) {
  const int ql = threadIdx.x & 15;
  const int qg = (blockIdx.x * NT + threadIdx.x) >> 4;
  const int nq = (gridDim.x * NT) >> 4;
  if (c.K == 96) {
    for (int v = qg; v < c.V; v += nq) {
      u64 pv = pack_key(c.hier[v], v);
      const int* row = c.neighs + (size_t)v * 96;
      int w[6];
#pragma unroll
      for (int t = 0; t < 6; ++t) w[t] = row[ql + 16 * t];
#pragma unroll
      for (int t = 0; t < 6; ++t)
        if (pack_key(c.hier[w[t]], w[t]) > pv) atomicAdd(&c.nsmall[w[t]], 1);
    }
  } else {
    for (int v = qg; v < c.V; v += nq) {
      u64 pv = pack_key(c.hier[v], v);
      const int* row = c.neighs + (size_t)v * c.K;
      for (int j = ql; j < c.K; j += 16) {
        int w = row[j];
        if (pack_key(c.hier[w], w) > pv) atomicAdd(&c.nsmall[w], 1);
      }
    }
  }
}

// ============ K1: seed scan — claim DAG roots into frontier (listA) ============
__global__ void __launch_bounds__(NT) k_seed(Ctx c) {
  __shared__ BlkState bs;
  if (threadIdx.x == 0) { bs.sc_cnt = 0; bs.sv_cnt = 0; }
  __syncthreads();
  const int gtid = blockIdx.x * NT + threadIdx.x;
  const int nthr = gridDim.x * NT;
  for (int v = gtid; v < c.V; v += nthr) {
    if (ald(&c.nsmall[v]) == 0 && atomicCAS(&c.nsmall[v], 0, CLAIM_SENT) == 0)
      push_succ(c, bs, c.listA, &c.cnt[0], v);        // CENTRE entry (no flag)
  }
  flush_block(c, bs, c.listA, &c.cnt[0]);
}

// ============ K2: tier-2 (16-block xbar rounds, large frontiers) ============
__global__ void __launch_bounds__(NT) k_t2(Ctx c) {
  __shared__ BlkState bs;
  const int ql = threadIdx.x & 15;
  const int NBQ = NT >> 4;
  const int qstart = blockIdx.x * NBQ + (threadIdx.x >> 4);
  const int qstride = TB2 * NBQ;
  if (threadIdx.x == 0) { bs.sc_cnt = 0; bs.sv_cnt = 0; }
  __syncthreads();

  int an = ald(&c.cnt[0]), r = 0, ep = 0;
  while (an > T2 && r < MAX_ROUNDS) {
    const int* rl = (r & 1) ? c.listB : c.listA;
    int* wl = (r & 1) ? c.listA : c.listB;
    int* survc = &c.cnt[(r + 1) & 1];
    if (blockIdx.x == 0 && threadIdx.x == 0) ast(survc, 0);
    xbar(&c.cnt[32], TB2 * (++ep));                   // reset visible to all
    prop_pass(c, bs, rl, wl, survc, an, qstart, qstride, ql);
    flush_block(c, bs, wl, survc);
    xbar(&c.cnt[32], TB2 * (++ep));
    an = ald(survc);
    ++r;
  }
  if (blockIdx.x == 0 && threadIdx.x == 0) { ast(&c.cnt[5], an); ast(&c.cnt[6], r); }
}

// ============ K3: tier-3 (single-block tail rounds) ============
__global__ void __launch_bounds__(NT) k_t3(Ctx c) {
  __shared__ BlkState bs;
  const int ql = threadIdx.x & 15;
  const int bq = threadIdx.x >> 4;
  const int NBQ = NT >> 4;
  if (threadIdx.x == 0) { bs.sc_cnt = 0; bs.sv_cnt = 0; }
  __syncthreads();

  int an = ald(&c.cnt[5]), r = ald(&c.cnt[6]);
  while (an > 0 && r < MAX_ROUNDS) {
    const int* rl = (r & 1) ? c.listB : c.listA;
    int* wl = (r & 1) ? c.listA : c.listB;
    int* survc = &c.cnt[(r + 1) & 1];
    if (threadIdx.x == 0) ast(survc, 0);
    __syncthreads();
    prop_pass(c, bs, rl, wl, survc, an, bq, NBQ, ql);
    flush_block(c, bs, wl, survc);
    __syncthreads();
    an = ald(survc);
    ++r;
  }
}

// ============ K4: centre ranks (O(nC^2) LDS-tiled) + row splits ============
__global__ void __launch_bounds__(NT) k_rank(Ctx c) {
  __shared__ u64 shp[NT];
  const int nC = c.cnt[4];
  for (int base = blockIdx.x * NT; base < nC; base += gridDim.x * NT) {
    int idx = base + threadIdx.x;
    bool have = idx < nC;
    u64 mykey = have ? c.centre_key[idx] : 0;
    int myv = have ? c.centre_v[idx] : 0;
    int myrank = 0;
    for (int cs = 0; cs < nC; cs += NT) {
      int j = cs + threadIdx.x;
      shp[threadIdx.x] = (j < nC) ? c.centre_key[j] : ~0ull;
      __syncthreads();
      int lim = min(NT, nC - cs);
      for (int t = 0; t < lim; ++t) myrank += (shp[t] < mykey) ? 1 : 0;
      __syncthreads();
    }
    if (have) {
      c.out_sel[myrank] = myv;   // rank among centre keys == cumsum position
      c.rank_of[myv] = myrank;
    }
  }
  if (blockIdx.x == 0 && threadIdx.x == 0) {
    int run = 0;
    c.out_rs[0] = 0;
    for (int s = 0; s < c.nseg; ++s) { run += c.cnt[8 + s]; c.out_rs[s + 1] = run; }
  }
}

// ============ K5: ggather ============
__global__ void __launch_bounds__(256) k_gg(Ctx c) {
  int v = blockIdx.x * blockDim.x + threadIdx.x;
  const int stride = gridDim.x * blockDim.x;
  for (; v < c.V; v += stride) {
    u64 y = c.assign[v];
    u64 pv = pack_key(c.hier[v], v);
    int ctr = (y < pv) ? (int)(y & IDX_MASK) : v;   // y>=pv (junk inert) -> self
    c.out_gg[v] = c.rank_of[ctr];
  }
}

extern "C" void kernel_launch(void* const* d_in, const int* in_sizes, int n_in,
                              void* d_out, int out_size, void* d_ws, size_t ws_size,
                              hipStream_t stream) {
  Ctx c;
  c.neighs = (const int*)d_in[0];
  c.hier = (const float*)d_in[1];
  c.row_splits = (const int*)d_in[2];
  c.V = in_sizes[1];
  c.K = in_sizes[0] / c.V;
  c.nseg = in_sizes[2] - 1;

  char* pm = (char*)d_ws;
  const size_t V = (size_t)c.V;
  c.assign = (u64*)pm;        pm += V * 8;   // -> ~0 (alive)
  c.nsmall = (int*)pm;        pm += V * 4;   // -> 0
  c.listA = (int*)pm;         pm += V * 4;
  c.listB = (int*)pm;         pm += V * 4;
  c.centre_key = (u64*)pm;    pm += V * 8;
  c.centre_v = (int*)pm;      pm += V * 4;
  c.rank_of = (int*)pm;       pm += V * 4;
  c.cnt = (int*)pm;           pm += 64 * 4;

  int* out = (int*)d_out;
  c.out_sel = out;
  c.out_rs = out + c.V;
  c.out_gg = out + c.V + c.nseg + 1;

  hipMemsetAsync(d_ws, 0xFF, V * 8, stream);            // assign
  hipMemsetAsync((void*)c.nsmall, 0, V * 4, stream);    // counters
  hipMemsetAsync((void*)c.cnt, 0, 64 * 4, stream);
  hipMemsetAsync((void*)c.out_sel, 0xFF, V * 4, stream);

  k_init<<<NB_INIT, NT, 0, stream>>>(c);
  k_seed<<<NB_INIT, NT, 0, stream>>>(c);
  k_t2<<<TB2, NT, 0, stream>>>(c);
  k_t3<<<1, NT, 0, stream>>>(c);
  k_rank<<<16, NT, 0, stream>>>(c);
  k_gg<<<512, 256, 0, stream>>>(c);
}

// Round 7
// 2148.051 us; speedup vs baseline: 2.1276x; 2.1276x over previous
//
#include <hip/hip_runtime.h>

#define IDX_BITS 20
#define IDX_MASK ((1u << IDX_BITS) - 1)
#define DEADF (1 << 30)
#define CLAIM_SENT (-(1 << 30))   // claimed; ±96 decrement noise stays in range
#define PARKED_D (-(1 << 29))     // parked dead job   (range [PARKED_D-4096, PARKED_D])
#define PARKED_C (-(1 << 28))     // parked centre job (range [PARKED_C-4096, PARKED_C])
#define NT 1024
#define NB_INIT 256
#define NBW 128                   // worker blocks (independent; no cross-block sync)
#define NQW (NT >> 4)             // 64 quarter-waves per block
#define LCAP 7168                 // per-list LDS entries (2 lists = 56 KB)
#define CHAIN_CAP 8               // max inline chain steps per micro-round
#define FIN_BLOCKS 16
#define MAX_FIN_ROUNDS 4000

typedef unsigned long long u64;

// All edges are intra-segment, so the per-edge comparison key drops seg:
// key = (~float_bits(hier) << 20) | v ; smaller = earlier in processing order.
__device__ __forceinline__ u64 pack_key(float h, int v) {
  return ((u64)(~__float_as_uint(h)) << IDX_BITS) | (unsigned)v;
}

__device__ __forceinline__ int ald(const int* p) {
  return __hip_atomic_load((int*)p, __ATOMIC_RELAXED, __HIP_MEMORY_SCOPE_AGENT);
}
__device__ __forceinline__ void ast(int* p, int v) {
  __hip_atomic_store(p, v, __ATOMIC_RELAXED, __HIP_MEMORY_SCOPE_AGENT);
}

// Claim algebra (R6, proven deterministic):
//   nsmall[u] = # smaller in-neighbours. CENTRE claims larger out-nbrs via
//   atomicExch (its kills; centres never decrement). DEAD decrements larger
//   out-nbrs; old==1 then CAS(0->CLAIM) claims a new CENTRE (all smaller
//   in-nbrs died). Claims are unique => each vertex is one job, each edge
//   touched O(1) times total. assign[] is output-only inert atomicMin.
// Execution (R7): NO global sync. Each block: seed-scan its slice, then
// micro-rounds over a block-local LDS worklist (cheap __syncthreads), with
// inline chaining (discoverer processes one successor, depth<=CHAIN_CAP per
// micro-round). Claimed work never crosses blocks => block exits when dry.
// Overflow -> PARK in nsmall[] sentinel + cnt[40] counter; k_fin sweeps.
struct Ctx {
  const int* __restrict__ neighs;
  const float* __restrict__ hier;
  const int* __restrict__ row_splits;
  int V, K, nseg;
  u64* assign;       // [V] min grabber key; ~0 alive; == own key -> centre
  int* nsmall;       // [V] dependency counters / claim state / park sentinels
  u64* centre_key;   // [V]
  int* centre_v;     // [V]
  int* rank_of;      // [V]
  int* cnt;          // [4]=nC, [8+s]=per-seg, [32]=fin xbar, [40]=parked, [41]=fin flag
  int* out_sel;
  int* out_rs;
  int* out_gg;
};

// Monotonic arrive-counter barrier (R2 form, proven) — k_fin only.
__device__ __forceinline__ void xbar(int* bar, int target) {
  __syncthreads();
  if (threadIdx.x == 0) {
    __hip_atomic_fetch_add(bar, 1, __ATOMIC_RELAXED, __HIP_MEMORY_SCOPE_AGENT);
    while (__hip_atomic_load(bar, __ATOMIC_RELAXED, __HIP_MEMORY_SCOPE_AGENT) < target)
      __builtin_amdgcn_s_sleep(2);
  }
  __syncthreads();
}

__device__ __forceinline__ void record_direct(const Ctx& c, int v, u64 pv) {
  int slot = atomicAdd(&c.cnt[4], 1);
  int seg = 0;
  for (int t = 1; t < c.nseg; ++t) seg += (v >= c.row_splits[t]);
  c.centre_v[slot] = v;
  c.centre_key[slot] = ((u64)seg << 52) | pv;
  atomicAdd(&c.cnt[8 + seg], 1);
}

// Park a CLAIMED job for the k_fin sweep. Counter bumped BEFORE the sentinel
// store so k_fin's decider never sees 0 with a sentinel pending.
__device__ __forceinline__ void park(const Ctx& c, int w, bool deadjob) {
  atomicAdd(&c.cnt[40], 1);
  ast(&c.nsmall[w], deadjob ? PARKED_D : PARKED_C);
}

// Process one claimed job with a quarter-wave (16 lanes). Returns the chained
// successor job (or -1). Non-chained successors go to the block LDS next-list
// (if nxt && room) else get PARKED. All per-lane successor bookkeeping is via
// bitmask + statically-indexed w[] (rule #20: no scratch in the hot path).
__device__ __forceinline__ int do_job(const Ctx& c, int job, int* nxt, int* nxtCnt,
                                      bool allow_chain, int ql, int lane) {
  const int v = job & IDX_MASK;
  const bool dead = (job & DEADF) != 0;
  const u64 pu = pack_key(c.hier[v], v);
  const int nf = dead ? 0 : DEADF;      // centre spawns DEAD jobs, dead spawns CENTRE
  int chain = -1;

  if (c.K == 96) {
    const int* row = c.neighs + (size_t)v * 96;
    int w[6]; u64 kw[6];
#pragma unroll
    for (int t = 0; t < 6; ++t) w[t] = row[ql + 16 * t];
#pragma unroll
    for (int t = 0; t < 6; ++t) kw[t] = pack_key(c.hier[w[t]], w[t]);
    unsigned sm = 0;
    if (!dead) {
#pragma unroll
      for (int t = 0; t < 6; ++t) atomicMin(&c.assign[w[t]], pu);   // inert junk ok
#pragma unroll
      for (int t = 0; t < 6; ++t)
        if (kw[t] > pu) {
          int old = atomicExch(&c.nsmall[w[t]], CLAIM_SENT);
          if (old >= 0) sm |= 1u << t;                               // newly DEAD
        }
      if (ql == 0) record_direct(c, v, pu);
    } else {
#pragma unroll
      for (int t = 0; t < 6; ++t)
        if (kw[t] > pu) {
          int old = atomicAdd(&c.nsmall[w[t]], -1);
          if (old == 1 && atomicCAS(&c.nsmall[w[t]], 0, CLAIM_SENT) == 0)
            sm |= 1u << t;                                           // newly CENTRE
        }
    }
    // chain: first lane in this 16-group with a successor donates one
    u64 bal = __ballot(sm != 0);
    unsigned bm = (unsigned)((bal >> (lane & 48)) & 0xFFFFull);
    if (allow_chain && bm) {
      int leader = __ffs(bm) - 1;
      int cand = -1;
      if (ql == leader) {
#pragma unroll
        for (int t = 0; t < 6; ++t)
          if (cand == -1 && (sm & (1u << t))) { cand = w[t] | nf; sm &= ~(1u << t); }
      }
      chain = __shfl(cand, leader, 16);
    }
    // push the rest: group prefix-sum, one shared atomicAdd by lane 0
    int ns = __popc(sm);
    int incl = ns;
#pragma unroll
    for (int d = 1; d < 16; d <<= 1) {
      int y = __shfl_up(incl, d, 16);
      if (ql >= d) incl += y;
    }
    int total = __shfl(incl, 15, 16);
    if (total > 0) {
      int base = -1;
      if (nxt) {
        if (ql == 0) base = atomicAdd(nxtCnt, total);
        base = __shfl(base, 0, 16);
      }
      int off = (base < 0 ? 0 : base) + incl - ns;
#pragma unroll
      for (int t = 0; t < 6; ++t)
        if (sm & (1u << t)) {
          int slot = off++;
          if (base >= 0 && slot < LCAP) nxt[slot] = w[t] | nf;
          else park(c, w[t], !dead);
        }
    }
  } else {
    // generic K (cold path): immediate park for all successors, no chaining
    const int* row = c.neighs + (size_t)v * c.K;
    if (!dead) {
      for (int j = ql; j < c.K; j += 16) atomicMin(&c.assign[row[j]], pu);
      for (int j = ql; j < c.K; j += 16) {
        int w = row[j];
        if (pack_key(c.hier[w], w) > pu) {
          int old = atomicExch(&c.nsmall[w], CLAIM_SENT);
          if (old >= 0) park(c, w, true);
        }
      }
      if (ql == 0) record_direct(c, v, pu);
    } else {
      for (int j = ql; j < c.K; j += 16) {
        int w = row[j];
        if (pack_key(c.hier[w], w) > pu) {
          int old = atomicAdd(&c.nsmall[w], -1);
          if (old == 1 && atomicCAS(&c.nsmall[w], 0, CLAIM_SENT) == 0)
            park(c, w, false);
        }
      }
    }
  }
  return chain;
}

// ============ K0: dependency-counter init (atomicAdd scatter) ============
__global__ void __launch_bounds__(NT) k_init(Ctx c) {
  const int ql = threadIdx.x & 15;
  const int qg = (blockIdx.x * NT + threadIdx.x) >> 4;
  const int nq = (gridDim.x * NT) >> 4;
  if (c.K == 96) {
    for (int v = qg; v < c.V; v += nq) {
      u64 pv = pack_key(c.hier[v], v);
      const int* row = c.neighs + (size_t)v * 96;
      int w[6];
#pragma unroll
      for (int t = 0; t < 6; ++t) w[t] = row[ql + 16 * t];
#pragma unroll
      for (int t = 0; t < 6; ++t)
        if (pack_key(c.hier[w[t]], w[t]) > pv) atomicAdd(&c.nsmall[w[t]], 1);
    }
  } else {
    for (int v = qg; v < c.V; v += nq) {
      u64 pv = pack_key(c.hier[v], v);
      const int* row = c.neighs + (size_t)v * c.K;
      for (int j = ql; j < c.K; j += 16) {
        int w = row[j];
        if (pack_key(c.hier[w], w) > pv) atomicAdd(&c.nsmall[w], 1);
      }
    }
  }
}

// ============ K1: independent worker blocks (seed + micro-round drain) ============
__global__ void __launch_bounds__(NT) k_work(Ctx c) {
  __shared__ int listX[LCAP], listY[LCAP];
  __shared__ int cntX, cntY;
  const int lane = threadIdx.x & 63;
  const int ql = threadIdx.x & 15;
  const int qw = threadIdx.x >> 4;

  if (threadIdx.x == 0) { cntX = 0; cntY = 0; }
  __syncthreads();

  // seed scan of own slice: zero counters are layer-0 centres
  long long vv0 = (long long)blockIdx.x * c.V / gridDim.x;
  long long vv1 = (long long)(blockIdx.x + 1) * c.V / gridDim.x;
  for (int v = (int)vv0 + threadIdx.x; v < (int)vv1; v += NT) {
    if (ald(&c.nsmall[v]) == 0 && atomicCAS(&c.nsmall[v], 0, CLAIM_SENT) == 0) {
      int s = atomicAdd(&cntX, 1);
      if (s < LCAP) listX[s] = v; else park(c, v, false);
    }
  }

  int phase = 0;
  while (true) {
    __syncthreads();
    int n = phase ? cntY : cntX;
    if (n == 0) break;
    n = min(n, LCAP);
    if (threadIdx.x == 0) { if (phase) cntX = 0; else cntY = 0; }
    __syncthreads();
    int* cur = phase ? listY : listX;
    int* nxt = phase ? listX : listY;
    int* nc  = phase ? &cntX : &cntY;
    for (int idx = qw; idx < n; idx += NQW) {
      int job = cur[idx];
      int steps = 0;
      while (job >= 0) {
        ++steps;
        job = do_job(c, job, nxt, nc, steps < CHAIN_CAP, ql, lane);
      }
    }
    phase ^= 1;
  }
}

// ============ K2: parked-work sweep (safety net; expected instant exit) ============
__global__ void __launch_bounds__(NT) k_fin(Ctx c) {
  const int lane = threadIdx.x & 63;
  const int ql = threadIdx.x & 15;
  const int qg = (blockIdx.x * NT + threadIdx.x) >> 4;
  const int nq = (FIN_BLOCKS * NT) >> 4;
  int ep = 0, rounds = 0;
  while (true) {
    if (blockIdx.x == 0 && threadIdx.x == 0)
      ast(&c.cnt[41], (ald(&c.cnt[40]) > 0 && rounds < MAX_FIN_ROUNDS) ? 1 : 0);
    xbar(&c.cnt[32], FIN_BLOCKS * (++ep));
    if (ald(&c.cnt[41]) == 0) break;              // uniform decision across blocks
    for (int v = qg; v < c.V; v += nq) {
      int x = ald(&c.nsmall[v]);
      bool pd = (x <= PARKED_D && x > PARKED_D - 4096);
      bool pc = (x <= PARKED_C && x > PARKED_C - 4096);
      if (!pd && !pc) continue;
      int won = 0;
      if (ql == 0 && atomicCAS(&c.nsmall[v], x, CLAIM_SENT) == x) won = 1;
      won = __shfl(won, 0, 16);
      if (!won) continue;                         // decrement race: retry next round
      if (ql == 0) atomicAdd(&c.cnt[40], -1);
      int job = pd ? (v | DEADF) : v;
      int steps = 0;
      while (job >= 0) {                          // chain; extra successors re-park
        ++steps;
        job = do_job(c, job, nullptr, nullptr, steps < 64, ql, lane);
      }
    }
    xbar(&c.cnt[32], FIN_BLOCKS * (++ep));
    ++rounds;
  }
}

// ============ K3: centre ranks (O(nC^2) LDS-tiled) + row splits ============
__global__ void __launch_bounds__(NT) k_rank(Ctx c) {
  __shared__ u64 shp[NT];
  const int nC = c.cnt[4];
  for (int base = blockIdx.x * NT; base < nC; base += gridDim.x * NT) {
    int idx = base + threadIdx.x;
    bool have = idx < nC;
    u64 mykey = have ? c.centre_key[idx] : 0;
    int myv = have ? c.centre_v[idx] : 0;
    int myrank = 0;
    for (int cs = 0; cs < nC; cs += NT) {
      int j = cs + threadIdx.x;
      shp[threadIdx.x] = (j < nC) ? c.centre_key[j] : ~0ull;
      __syncthreads();
      int lim = min(NT, nC - cs);
      for (int t = 0; t < lim; ++t) myrank += (shp[t] < mykey) ? 1 : 0;
      __syncthreads();
    }
    if (have) {
      c.out_sel[myrank] = myv;   // rank among centre keys == cumsum position
      c.rank_of[myv] = myrank;
    }
  }
  if (blockIdx.x == 0 && threadIdx.x == 0) {
    int run = 0;
    c.out_rs[0] = 0;
    for (int s = 0; s < c.nseg; ++s) { run += c.cnt[8 + s]; c.out_rs[s + 1] = run; }
  }
}

// ============ K4: ggather ============
__global__ void __launch_bounds__(256) k_gg(Ctx c) {
  int v = blockIdx.x * blockDim.x + threadIdx.x;
  const int stride = gridDim.x * blockDim.x;
  for (; v < c.V; v += stride) {
    u64 y = c.assign[v];
    u64 pv = pack_key(c.hier[v], v);
    int ctr = (y < pv) ? (int)(y & IDX_MASK) : v;   // y>=pv -> centre -> self
    c.out_gg[v] = c.rank_of[ctr];
  }
}

extern "C" void kernel_launch(void* const* d_in, const int* in_sizes, int n_in,
                              void* d_out, int out_size, void* d_ws, size_t ws_size,
                              hipStream_t stream) {
  Ctx c;
  c.neighs = (const int*)d_in[0];
  c.hier = (const float*)d_in[1];
  c.row_splits = (const int*)d_in[2];
  c.V = in_sizes[1];
  c.K = in_sizes[0] / c.V;
  c.nseg = in_sizes[2] - 1;

  char* pm = (char*)d_ws;
  const size_t V = (size_t)c.V;
  c.assign = (u64*)pm;        pm += V * 8;   // -> ~0 (alive)
  c.nsmall = (int*)pm;        pm += V * 4;   // -> 0
  c.centre_key = (u64*)pm;    pm += V * 8;
  c.centre_v = (int*)pm;      pm += V * 4;
  c.rank_of = (int*)pm;       pm += V * 4;
  c.cnt = (int*)pm;           pm += 64 * 4;

  int* out = (int*)d_out;
  c.out_sel = out;
  c.out_rs = out + c.V;
  c.out_gg = out + c.V + c.nseg + 1;

  hipMemsetAsync(d_ws, 0xFF, V * 8, stream);            // assign
  hipMemsetAsync((void*)c.nsmall, 0, V * 4, stream);    // counters
  hipMemsetAsync((void*)c.cnt, 0, 64 * 4, stream);
  hipMemsetAsync((void*)c.out_sel, 0xFF, V * 4, stream);

  k_init<<<NB_INIT, NT, 0, stream>>>(c);
  k_work<<<NBW, NT, 0, stream>>>(c);
  k_fin<<<FIN_BLOCKS, NT, 0, stream>>>(c);
  k_rank<<<16, NT, 0, stream>>>(c);
  k_gg<<<512, 256, 0, stream>>>(c);
}

// Round 8
// 2086.902 us; speedup vs baseline: 2.1899x; 1.0293x over previous
//
#include <hip/hip_runtime.h>

#define IDX_BITS 20
#define IDX_MASK ((1u << IDX_BITS) - 1)
#define DEADF (1 << 30)
#define CLAIM_SENT (-(1 << 30))   // claimed; ±96 decrement noise stays in range
#define PARKED_D (-(1 << 29))     // parked dead job   (range [PARKED_D-4096, PARKED_D])
#define PARKED_C (-(1 << 28))     // parked centre job (range [PARKED_C-4096, PARKED_C])
#define NT 1024
#define NBW 128                   // cooperative worker blocks (co-resident)
#define NQW (NT >> 4)             // 64 quarter-waves per block
#define LCAP 7168                 // per-list LDS entries (2 lists = 56 KB)
#define CHAIN_CAP 32              // inline chain depth per micro-round
#define FIN_BLOCKS 16
#define MAX_FIN_ROUNDS 4000

typedef unsigned long long u64;

// All edges are intra-segment, so the per-edge comparison key drops seg:
// key = (~float_bits(hier) << 20) | v ; smaller = earlier in processing order.
__device__ __forceinline__ u64 pack_key(float h, int v) {
  return ((u64)(~__float_as_uint(h)) << IDX_BITS) | (unsigned)v;
}

__device__ __forceinline__ int ald(const int* p) {
  return __hip_atomic_load((int*)p, __ATOMIC_RELAXED, __HIP_MEMORY_SCOPE_AGENT);
}
__device__ __forceinline__ void ast(int* p, int v) {
  __hip_atomic_store(p, v, __ATOMIC_RELAXED, __HIP_MEMORY_SCOPE_AGENT);
}

// Claim algebra (R6/R7, proven):
//   nsmall[u] = # smaller in-neighbours. CENTRE claims larger out-nbrs via
//   atomicExch (its kills; centres never decrement). DEAD decrements larger
//   out-nbrs; old==1 means ALL smaller in-nbrs died => w is a CENTRE, and
//   (key point, R8) NO exch can ever target w (none of its smaller in-nbrs
//   is a centre) => old==1 alone is a unique claim. The CAS that guarded the
//   seed race is gone: seeding completes grid-wide (xbar) before any drain.
// Execution: ONE cooperative kernel: init -> xbar -> seed own slice
// (exclusive => plain claim) -> xbar -> block-local micro-round drain with
// inline chaining (CHAIN_CAP links per micro-round). Claimed work never
// crosses blocks. Overflow -> PARK sentinel in nsmall[] + cnt[40]; k_fin sweeps.
struct Ctx {
  const int* __restrict__ neighs;
  const float* __restrict__ hier;
  const int* __restrict__ row_splits;
  int V, K, nseg;
  u64* assign;       // [V] min grabber key; ~0 alive; == own key -> centre
  int* nsmall;       // [V] dependency counters / claim state / park sentinels
  u64* centre_key;   // [V]
  int* centre_v;     // [V]
  int* rank_of;      // [V]
  int* cnt;          // [4]=nC, [8+s]=per-seg, [32]=fin xbar, [40]=parked, [41]=fin flag, [48]=main xbar
  int* out_sel;
  int* out_rs;
  int* out_gg;
};

// Monotonic arrive-counter barrier (R2 form, proven).
__device__ __forceinline__ void xbar(int* bar, int target) {
  __syncthreads();
  if (threadIdx.x == 0) {
    __hip_atomic_fetch_add(bar, 1, __ATOMIC_RELAXED, __HIP_MEMORY_SCOPE_AGENT);
    while (__hip_atomic_load(bar, __ATOMIC_RELAXED, __HIP_MEMORY_SCOPE_AGENT) < target)
      __builtin_amdgcn_s_sleep(2);
  }
  __syncthreads();
}

__device__ __forceinline__ void record_direct(const Ctx& c, int v, u64 pv) {
  int slot = atomicAdd(&c.cnt[4], 1);
  int seg = 0;
  for (int t = 1; t < c.nseg; ++t) seg += (v >= c.row_splits[t]);
  c.centre_v[slot] = v;
  c.centre_key[slot] = ((u64)seg << 52) | pv;
  atomicAdd(&c.cnt[8 + seg], 1);
}

// Park a CLAIMED job for the k_fin sweep (counter bumped BEFORE sentinel).
__device__ __forceinline__ void park(const Ctx& c, int w, bool deadjob) {
  atomicAdd(&c.cnt[40], 1);
  ast(&c.nsmall[w], deadjob ? PARKED_D : PARKED_C);
}

// Process one claimed job with a quarter-wave (16 lanes). Returns the chained
// successor (or -1). Non-chained successors -> block LDS next-list (if nxt &&
// room) else PARKED. CAS-free: dead-path old==1 is itself the unique claim.
__device__ __forceinline__ int do_job(const Ctx& c, int job, int* nxt, int* nxtCnt,
                                      bool allow_chain, int ql, int lane) {
  const int v = job & IDX_MASK;
  const bool dead = (job & DEADF) != 0;
  const u64 pu = pack_key(c.hier[v], v);
  const int nf = dead ? 0 : DEADF;      // centre spawns DEAD jobs, dead spawns CENTRE
  int chain = -1;

  if (c.K == 96) {
    const int* row = c.neighs + (size_t)v * 96;
    int w[6]; u64 kw[6];
#pragma unroll
    for (int t = 0; t < 6; ++t) w[t] = row[ql + 16 * t];
#pragma unroll
    for (int t = 0; t < 6; ++t) kw[t] = pack_key(c.hier[w[t]], w[t]);
    unsigned sm = 0;
    if (!dead) {
#pragma unroll
      for (int t = 0; t < 6; ++t) atomicMin(&c.assign[w[t]], pu);   // inert junk ok
#pragma unroll
      for (int t = 0; t < 6; ++t)
        if (kw[t] > pu) {
          int old = atomicExch(&c.nsmall[w[t]], CLAIM_SENT);
          if (old >= 0) sm |= 1u << t;                               // newly DEAD
        }
      if (ql == 0) record_direct(c, v, pu);
    } else {
#pragma unroll
      for (int t = 0; t < 6; ++t)
        if (kw[t] > pu) {
          int old = atomicAdd(&c.nsmall[w[t]], -1);
          if (old == 1) sm |= 1u << t;           // unique claim: newly CENTRE
        }
    }
    // chain: first lane in this 16-group with a successor donates one
    u64 bal = __ballot(sm != 0);
    unsigned bm = (unsigned)((bal >> (lane & 48)) & 0xFFFFull);
    if (allow_chain && bm) {
      int leader = __ffs(bm) - 1;
      int cand = -1;
      if (ql == leader) {
#pragma unroll
        for (int t = 0; t < 6; ++t)
          if (cand == -1 && (sm & (1u << t))) { cand = w[t] | nf; sm &= ~(1u << t); }
      }
      chain = __shfl(cand, leader, 16);
    }
    // push the rest: group prefix-sum, one shared atomicAdd by lane 0
    int ns = __popc(sm);
    int incl = ns;
#pragma unroll
    for (int d = 1; d < 16; d <<= 1) {
      int y = __shfl_up(incl, d, 16);
      if (ql >= d) incl += y;
    }
    int total = __shfl(incl, 15, 16);
    if (total > 0) {
      int base = -1;
      if (nxt) {
        if (ql == 0) base = atomicAdd(nxtCnt, total);
        base = __shfl(base, 0, 16);
      }
      int off = (base < 0 ? 0 : base) + incl - ns;
#pragma unroll
      for (int t = 0; t < 6; ++t)
        if (sm & (1u << t)) {
          int slot = off++;
          if (base >= 0 && slot < LCAP) nxt[slot] = w[t] | nf;
          else park(c, w[t], !dead);
        }
    }
  } else {
    // generic K (cold path): park successors, no chaining
    const int* row = c.neighs + (size_t)v * c.K;
    if (!dead) {
      for (int j = ql; j < c.K; j += 16) atomicMin(&c.assign[row[j]], pu);
      for (int j = ql; j < c.K; j += 16) {
        int w = row[j];
        if (pack_key(c.hier[w], w) > pu) {
          int old = atomicExch(&c.nsmall[w], CLAIM_SENT);
          if (old >= 0) park(c, w, true);
        }
      }
      if (ql == 0) record_direct(c, v, pu);
    } else {
      for (int j = ql; j < c.K; j += 16) {
        int w = row[j];
        if (pack_key(c.hier[w], w) > pu) {
          int old = atomicAdd(&c.nsmall[w], -1);
          if (old == 1) park(c, w, false);
        }
      }
    }
  }
  return chain;
}

// ============ K1: cooperative main — init + seed + block-local drain ============
__global__ void __launch_bounds__(NT) k_main(Ctx c) {
  __shared__ int listX[LCAP], listY[LCAP];
  __shared__ int cntX, cntY;
  const int lane = threadIdx.x & 63;
  const int ql = threadIdx.x & 15;
  const int qw = threadIdx.x >> 4;
  const int nb = gridDim.x;

  if (threadIdx.x == 0) { cntX = 0; cntY = 0; }

  // ---- phase 1: dependency-counter init (grid-strided scatter) ----
  {
    const int qg = (blockIdx.x * NT + threadIdx.x) >> 4;
    const int nq = (nb * NT) >> 4;
    if (c.K == 96) {
      for (int v = qg; v < c.V; v += nq) {
        u64 pv = pack_key(c.hier[v], v);
        const int* row = c.neighs + (size_t)v * 96;
        int w[6];
#pragma unroll
        for (int t = 0; t < 6; ++t) w[t] = row[ql + 16 * t];
#pragma unroll
        for (int t = 0; t < 6; ++t)
          if (pack_key(c.hier[w[t]], w[t]) > pv) atomicAdd(&c.nsmall[w[t]], 1);
      }
    } else {
      for (int v = qg; v < c.V; v += nq) {
        u64 pv = pack_key(c.hier[v], v);
        const int* row = c.neighs + (size_t)v * c.K;
        for (int j = ql; j < c.K; j += 16) {
          int w = row[j];
          if (pack_key(c.hier[w], w) > pv) atomicAdd(&c.nsmall[w], 1);
        }
      }
    }
  }
  xbar(&c.cnt[48], nb * 1);     // all counters final before any seed read

  // ---- phase 2: seed own slice (exclusive => plain claim, no CAS) ----
  {
    long long vv0 = (long long)blockIdx.x * c.V / nb;
    long long vv1 = (long long)(blockIdx.x + 1) * c.V / nb;
    for (int v = (int)vv0 + threadIdx.x; v < (int)vv1; v += NT) {
      if (ald(&c.nsmall[v]) == 0) {
        ast(&c.nsmall[v], CLAIM_SENT);
        int s = atomicAdd(&cntX, 1);
        if (s < LCAP) listX[s] = v; else park(c, v, false);
      }
    }
  }
  xbar(&c.cnt[48], nb * 2);     // all seeds claimed before any decrement flies

  // ---- phase 3: block-local micro-round drain with inline chaining ----
  int phase = 0;
  while (true) {
    __syncthreads();
    int n = phase ? cntY : cntX;
    if (n == 0) break;
    n = min(n, LCAP);
    if (threadIdx.x == 0) { if (phase) cntX = 0; else cntY = 0; }
    __syncthreads();
    int* cur = phase ? listY : listX;
    int* nxt = phase ? listX : listY;
    int* nc  = phase ? &cntX : &cntY;
    for (int idx = qw; idx < n; idx += NQW) {
      int job = cur[idx];
      int steps = 0;
      while (job >= 0) {
        ++steps;
        job = do_job(c, job, nxt, nc, steps < CHAIN_CAP, ql, lane);
      }
    }
    phase ^= 1;
  }
}

// ============ K2: parked-work sweep (safety net; expected instant exit) ============
__global__ void __launch_bounds__(NT) k_fin(Ctx c) {
  const int lane = threadIdx.x & 63;
  const int ql = threadIdx.x & 15;
  const int qg = (blockIdx.x * NT + threadIdx.x) >> 4;
  const int nq = (FIN_BLOCKS * NT) >> 4;
  int ep = 0, rounds = 0;
  while (true) {
    if (blockIdx.x == 0 && threadIdx.x == 0)
      ast(&c.cnt[41], (ald(&c.cnt[40]) > 0 && rounds < MAX_FIN_ROUNDS) ? 1 : 0);
    xbar(&c.cnt[32], FIN_BLOCKS * (++ep));
    if (ald(&c.cnt[41]) == 0) break;              // uniform decision across blocks
    for (int v = qg; v < c.V; v += nq) {
      int x = ald(&c.nsmall[v]);
      bool pd = (x <= PARKED_D && x > PARKED_D - 4096);
      bool pc = (x <= PARKED_C && x > PARKED_C - 4096);
      if (!pd && !pc) continue;
      int won = 0;
      if (ql == 0 && atomicCAS(&c.nsmall[v], x, CLAIM_SENT) == x) won = 1;
      won = __shfl(won, 0, 16);
      if (!won) continue;                         // decrement race: retry next round
      if (ql == 0) atomicAdd(&c.cnt[40], -1);
      int job = pd ? (v | DEADF) : v;
      int steps = 0;
      while (job >= 0) {                          // chain; extra successors re-park
        ++steps;
        job = do_job(c, job, nullptr, nullptr, steps < 64, ql, lane);
      }
    }
    xbar(&c.cnt[32], FIN_BLOCKS * (++ep));
    ++rounds;
  }
}

// ============ K3: centre ranks (O(nC^2) LDS-tiled) + row splits ============
__global__ void __launch_bounds__(NT) k_rank(Ctx c) {
  __shared__ u64 shp[NT];
  const int nC = c.cnt[4];
  for (int base = blockIdx.x * NT; base < nC; base += gridDim.x * NT) {
    int idx = base + threadIdx.x;
    bool have = idx < nC;
    u64 mykey = have ? c.centre_key[idx] : 0;
    int myv = have ? c.centre_v[idx] : 0;
    int myrank = 0;
    for (int cs = 0; cs < nC; cs += NT) {
      int j = cs + threadIdx.x;
      shp[threadIdx.x] = (j < nC) ? c.centre_key[j] : ~0ull;
      __syncthreads();
      int lim = min(NT, nC - cs);
      for (int t = 0; t < lim; ++t) myrank += (shp[t] < mykey) ? 1 : 0;
      __syncthreads();
    }
    if (have) {
      c.out_sel[myrank] = myv;   // rank among centre keys == cumsum position
      c.rank_of[myv] = myrank;
    }
  }
  if (blockIdx.x == 0 && threadIdx.x == 0) {
    int run = 0;
    c.out_rs[0] = 0;
    for (int s = 0; s < c.nseg; ++s) { run += c.cnt[8 + s]; c.out_rs[s + 1] = run; }
  }
}

// ============ K4: ggather ============
__global__ void __launch_bounds__(256) k_gg(Ctx c) {
  int v = blockIdx.x * blockDim.x + threadIdx.x;
  const int stride = gridDim.x * blockDim.x;
  for (; v < c.V; v += stride) {
    u64 y = c.assign[v];
    u64 pv = pack_key(c.hier[v], v);
    int ctr = (y < pv) ? (int)(y & IDX_MASK) : v;   // y>=pv -> centre -> self
    c.out_gg[v] = c.rank_of[ctr];
  }
}

extern "C" void kernel_launch(void* const* d_in, const int* in_sizes, int n_in,
                              void* d_out, int out_size, void* d_ws, size_t ws_size,
                              hipStream_t stream) {
  Ctx c;
  c.neighs = (const int*)d_in[0];
  c.hier = (const float*)d_in[1];
  c.row_splits = (const int*)d_in[2];
  c.V = in_sizes[1];
  c.K = in_sizes[0] / c.V;
  c.nseg = in_sizes[2] - 1;

  char* pm = (char*)d_ws;
  const size_t V = (size_t)c.V;
  c.assign = (u64*)pm;        pm += V * 8;   // -> ~0 (alive)
  c.nsmall = (int*)pm;        pm += V * 4;   // -> 0
  c.centre_key = (u64*)pm;    pm += V * 8;
  c.centre_v = (int*)pm;      pm += V * 4;
  c.rank_of = (int*)pm;       pm += V * 4;
  c.cnt = (int*)pm;           pm += 64 * 4;

  int* out = (int*)d_out;
  c.out_sel = out;
  c.out_rs = out + c.V;
  c.out_gg = out + c.V + c.nseg + 1;

  hipMemsetAsync(d_ws, 0xFF, V * 8, stream);            // assign
  hipMemsetAsync((void*)c.nsmall, 0, V * 4, stream);    // counters
  hipMemsetAsync((void*)c.cnt, 0, 64 * 4, stream);
  hipMemsetAsync((void*)c.out_sel, 0xFF, V * 4, stream);

  void* args[] = { &c };
  hipLaunchCooperativeKernel((void*)k_main, dim3(NBW), dim3(NT), args, 0, stream);
  k_fin<<<FIN_BLOCKS, NT, 0, stream>>>(c);
  k_rank<<<16, NT, 0, stream>>>(c);
  k_gg<<<512, 256, 0, stream>>>(c);
}

// Round 9
// 1732.443 us; speedup vs baseline: 2.6380x; 1.2046x over previous
//
#include <hip/hip_runtime.h>

#define IDX_BITS 20
#define IDX_MASK ((1u << IDX_BITS) - 1)
#define DEADF (1 << 30)
#define CLAIM_SENT (-(1 << 30))   // claimed; ±96 decrement noise stays in range
#define PARKED_D (-(1 << 29))     // parked dead job   (range [PARKED_D-4096, PARKED_D])
#define PARKED_C (-(1 << 28))     // parked centre job (range [PARKED_C-4096, PARKED_C])
#define NT 1024
#define NBW 256                   // cooperative blocks: 1/CU (57.4KB LDS -> 2/CU possible)
#define NQW (NT >> 4)             // 64 quarter-waves per block
#define LCAP 7168                 // per-list LDS entries (2 lists = 56 KB)
#define CHAIN_CAP 32              // inline chain depth per micro-round
#define MAX_FIN_ROUNDS 4000

typedef unsigned long long u64;

// All edges are intra-segment, so the per-edge comparison key drops seg:
// key = (~float_bits(hier) << 20) | v ; smaller = earlier in processing order.
__device__ __forceinline__ u64 pack_key(float h, int v) {
  return ((u64)(~__float_as_uint(h)) << IDX_BITS) | (unsigned)v;
}

__device__ __forceinline__ int ald(const int* p) {
  return __hip_atomic_load((int*)p, __ATOMIC_RELAXED, __HIP_MEMORY_SCOPE_AGENT);
}
__device__ __forceinline__ u64 ald64(const u64* p) {
  return __hip_atomic_load((u64*)p, __ATOMIC_RELAXED, __HIP_MEMORY_SCOPE_AGENT);
}
__device__ __forceinline__ void ast(int* p, int v) {
  __hip_atomic_store(p, v, __ATOMIC_RELAXED, __HIP_MEMORY_SCOPE_AGENT);
}
__device__ __forceinline__ void ast64(u64* p, u64 v) {
  __hip_atomic_store(p, v, __ATOMIC_RELAXED, __HIP_MEMORY_SCOPE_AGENT);
}

// Claim algebra (R6-R8, proven):
//   nsmall[u] = # smaller in-neighbours. CENTRE claims larger out-nbrs via
//   atomicExch (its kills; centres never decrement). DEAD decrements larger
//   out-nbrs; old==1 means ALL smaller in-nbrs died => w is a CENTRE and no
//   exch can ever target it => old==1 alone is a unique claim (CAS-free).
//   Seeding completes grid-wide (xbar) before any decrement flies.
// R9: ONE cooperative kernel for everything: init(+kmask) -> xbar -> seed ->
// xbar -> block-local chained drain -> xbar -> parked sweep -> rank -> gg.
// kmask[v] = per-lane 6-bit "neighbour has larger key" masks (packed 16B/vtx)
// so drain jobs never re-gather hier: critical-path link = decrement return ->
// row load + kmask word -> next decrements.
struct Ctx {
  const int* __restrict__ neighs;
  const float* __restrict__ hier;
  const int* __restrict__ row_splits;
  int V, K, nseg;
  u64* assign;       // [V] min grabber key; ~0 alive; == own key -> centre
  int* nsmall;       // [V] dependency counters / claim state / park sentinels
  int* kmask;        // [V*4] packed per-lane larger-key masks (K==96 only)
  u64* centre_key;   // [V]
  int* centre_v;     // [V]
  int* rank_of;      // [V]
  int* cnt;          // [4]=nC, [8+s]=per-seg, [40]=parked, [41]=fin flag, [48]=xbar
  int* out_sel;
  int* out_rs;
  int* out_gg;
};

// Monotonic arrive-counter barrier (R2 form, proven).
__device__ __forceinline__ void xbar(int* bar, int target) {
  __syncthreads();
  if (threadIdx.x == 0) {
    __hip_atomic_fetch_add(bar, 1, __ATOMIC_RELAXED, __HIP_MEMORY_SCOPE_AGENT);
    while (__hip_atomic_load(bar, __ATOMIC_RELAXED, __HIP_MEMORY_SCOPE_AGENT) < target)
      __builtin_amdgcn_s_sleep(2);
  }
  __syncthreads();
}

// Centre arrays via agent atomics: read later in-kernel by other blocks.
__device__ __forceinline__ void record_direct(const Ctx& c, int v, u64 pv) {
  int slot = atomicAdd(&c.cnt[4], 1);
  int seg = 0;
  for (int t = 1; t < c.nseg; ++t) seg += (v >= c.row_splits[t]);
  ast(&c.centre_v[slot], v);
  ast64(&c.centre_key[slot], ((u64)seg << 52) | pv);
  atomicAdd(&c.cnt[8 + seg], 1);
}

// Park a CLAIMED job for the fin sweep (counter bumped BEFORE sentinel).
__device__ __forceinline__ void park(const Ctx& c, int w, bool deadjob) {
  atomicAdd(&c.cnt[40], 1);
  ast(&c.nsmall[w], deadjob ? PARKED_D : PARKED_C);
}

// Process one claimed job with a quarter-wave (16 lanes). Returns the chained
// successor (or -1). Non-chained successors -> block LDS next-list (if nxt &&
// room) else PARKED. kmask replaces all hier gathers on the K==96 hot path.
__device__ __forceinline__ int do_job(const Ctx& c, int job, int* nxt, int* nxtCnt,
                                      bool allow_chain, int ql, int lane) {
  const int v = job & IDX_MASK;
  const bool dead = (job & DEADF) != 0;
  const u64 pu = pack_key(c.hier[v], v);
  const int nf = dead ? 0 : DEADF;      // centre spawns DEAD jobs, dead spawns CENTRE
  int chain = -1;

  if (c.K == 96) {
    const int* row = c.neighs + (size_t)v * 96;
    int w[6];
#pragma unroll
    for (int t = 0; t < 6; ++t) w[t] = row[ql + 16 * t];
    int kmw = ald(&c.kmask[(size_t)v * 4 + (ql >> 2)]);
    unsigned km = ((unsigned)kmw >> ((ql & 3) * 8)) & 63u;
    unsigned sm = 0;
    if (!dead) {
#pragma unroll
      for (int t = 0; t < 6; ++t) atomicMin(&c.assign[w[t]], pu);   // inert junk ok
#pragma unroll
      for (int t = 0; t < 6; ++t)
        if (km & (1u << t)) {
          int old = atomicExch(&c.nsmall[w[t]], CLAIM_SENT);
          if (old >= 0) sm |= 1u << t;                               // newly DEAD
        }
      if (ql == 0) record_direct(c, v, pu);
    } else {
#pragma unroll
      for (int t = 0; t < 6; ++t)
        if (km & (1u << t)) {
          int old = atomicAdd(&c.nsmall[w[t]], -1);
          if (old == 1) sm |= 1u << t;           // unique claim: newly CENTRE
        }
    }
    // chain: first lane in this 16-group with a successor donates one
    u64 bal = __ballot(sm != 0);
    unsigned bm = (unsigned)((bal >> (lane & 48)) & 0xFFFFull);
    if (allow_chain && bm) {
      int leader = __ffs(bm) - 1;
      int cand = -1;
      if (ql == leader) {
#pragma unroll
        for (int t = 0; t < 6; ++t)
          if (cand == -1 && (sm & (1u << t))) { cand = w[t] | nf; sm &= ~(1u << t); }
      }
      chain = __shfl(cand, leader, 16);
    }
    // push the rest: group prefix-sum, one shared atomicAdd by lane 0
    int ns = __popc(sm);
    int incl = ns;
#pragma unroll
    for (int d = 1; d < 16; d <<= 1) {
      int y = __shfl_up(incl, d, 16);
      if (ql >= d) incl += y;
    }
    int total = __shfl(incl, 15, 16);
    if (total > 0) {
      int base = -1;
      if (nxt) {
        if (ql == 0) base = atomicAdd(nxtCnt, total);
        base = __shfl(base, 0, 16);
      }
      int off = (base < 0 ? 0 : base) + incl - ns;
#pragma unroll
      for (int t = 0; t < 6; ++t)
        if (sm & (1u << t)) {
          int slot = off++;
          if (base >= 0 && slot < LCAP) nxt[slot] = w[t] | nf;
          else park(c, w[t], !dead);
        }
    }
  } else {
    // generic K (cold path): hier gathers, park successors, no chaining
    const int* row = c.neighs + (size_t)v * c.K;
    if (!dead) {
      for (int j = ql; j < c.K; j += 16) atomicMin(&c.assign[row[j]], pu);
      for (int j = ql; j < c.K; j += 16) {
        int w = row[j];
        if (pack_key(c.hier[w], w) > pu) {
          int old = atomicExch(&c.nsmall[w], CLAIM_SENT);
          if (old >= 0) park(c, w, true);
        }
      }
      if (ql == 0) record_direct(c, v, pu);
    } else {
      for (int j = ql; j < c.K; j += 16) {
        int w = row[j];
        if (pack_key(c.hier[w], w) > pu) {
          int old = atomicAdd(&c.nsmall[w], -1);
          if (old == 1) park(c, w, false);
        }
      }
    }
  }
  return chain;
}

// ============ K1: one cooperative kernel — everything ============
__global__ void __launch_bounds__(NT) k_main(Ctx c) {
  __shared__ __align__(16) int listX[LCAP];
  __shared__ __align__(16) int listY[LCAP];
  __shared__ int cntX, cntY;
  const int lane = threadIdx.x & 63;
  const int ql = threadIdx.x & 15;
  const int qw = threadIdx.x >> 4;
  const int nb = gridDim.x;
  int ep = 0;

  if (threadIdx.x == 0) { cntX = 0; cntY = 0; }

  // ---- phase 1: dependency-counter init + kmask build ----
  {
    const int qg = (blockIdx.x * NT + threadIdx.x) >> 4;
    const int nq = (nb * NT) >> 4;
    if (c.K == 96) {
      for (int v = qg; v < c.V; v += nq) {
        u64 pv = pack_key(c.hier[v], v);
        const int* row = c.neighs + (size_t)v * 96;
        int w[6];
#pragma unroll
        for (int t = 0; t < 6; ++t) w[t] = row[ql + 16 * t];
        unsigned m = 0;
#pragma unroll
        for (int t = 0; t < 6; ++t)
          if (pack_key(c.hier[w[t]], w[t]) > pv) {
            m |= 1u << t;
            atomicAdd(&c.nsmall[w[t]], 1);
          }
        // pack 4 lanes' 6-bit masks per 32-bit word (byte-per-lane)
        unsigned pk = m;
        pk |= ((unsigned)__shfl((int)m, (lane + 1) & 63) << 8);
        pk |= ((unsigned)__shfl((int)m, (lane + 2) & 63) << 16);
        pk |= ((unsigned)__shfl((int)m, (lane + 3) & 63) << 24);
        if ((ql & 3) == 0) ast(&c.kmask[(size_t)v * 4 + (ql >> 2)], (int)pk);
      }
    } else {
      for (int v = qg; v < c.V; v += nq) {
        u64 pv = pack_key(c.hier[v], v);
        const int* row = c.neighs + (size_t)v * c.K;
        for (int j = ql; j < c.K; j += 16) {
          int w = row[j];
          if (pack_key(c.hier[w], w) > pv) atomicAdd(&c.nsmall[w], 1);
        }
      }
    }
  }
  xbar(&c.cnt[48], nb * (++ep));   // counters + kmask final before any seed read

  // ---- phase 2: seed own slice (exclusive => plain claim, no CAS) ----
  {
    long long vv0 = (long long)blockIdx.x * c.V / nb;
    long long vv1 = (long long)(blockIdx.x + 1) * c.V / nb;
    for (int v = (int)vv0 + threadIdx.x; v < (int)vv1; v += NT) {
      if (ald(&c.nsmall[v]) == 0) {
        ast(&c.nsmall[v], CLAIM_SENT);
        int s = atomicAdd(&cntX, 1);
        if (s < LCAP) listX[s] = v; else park(c, v, false);
      }
    }
  }
  xbar(&c.cnt[48], nb * (++ep));   // all seeds claimed before any decrement flies

  // ---- phase 3: block-local micro-round drain with inline chaining ----
  {
    int phase = 0;
    while (true) {
      __syncthreads();
      int n = phase ? cntY : cntX;
      if (n == 0) break;
      n = min(n, LCAP);
      if (threadIdx.x == 0) { if (phase) cntX = 0; else cntY = 0; }
      __syncthreads();
      int* cur = phase ? listY : listX;
      int* nxt = phase ? listX : listY;
      int* nc  = phase ? &cntX : &cntY;
      for (int idx = qw; idx < n; idx += NQW) {
        int job = cur[idx];
        int steps = 0;
        while (job >= 0) {
          ++steps;
          job = do_job(c, job, nxt, nc, steps < CHAIN_CAP, ql, lane);
        }
      }
      phase ^= 1;
    }
  }
  xbar(&c.cnt[48], nb * (++ep));   // all blocks dry

  // ---- phase 4: parked-work sweep (safety net; expected instant exit) ----
  {
    const int qg = (blockIdx.x * NT + threadIdx.x) >> 4;
    const int nq = (nb * NT) >> 4;
    int rounds = 0;
    while (true) {
      if (blockIdx.x == 0 && threadIdx.x == 0)
        ast(&c.cnt[41], (ald(&c.cnt[40]) > 0 && rounds < MAX_FIN_ROUNDS) ? 1 : 0);
      xbar(&c.cnt[48], nb * (++ep));
      if (ald(&c.cnt[41]) == 0) break;            // uniform decision
      for (int v = qg; v < c.V; v += nq) {
        int x = ald(&c.nsmall[v]);
        bool pd = (x <= PARKED_D && x > PARKED_D - 4096);
        bool pc = (x <= PARKED_C && x > PARKED_C - 4096);
        if (!pd && !pc) continue;
        int won = 0;
        if (ql == 0 && atomicCAS(&c.nsmall[v], x, CLAIM_SENT) == x) won = 1;
        won = __shfl(won, 0, 16);
        if (!won) continue;                       // decrement race: retry next round
        if (ql == 0) atomicAdd(&c.cnt[40], -1);
        int job = pd ? (v | DEADF) : v;
        int steps = 0;
        while (job >= 0) {                        // chain; extra successors re-park
          ++steps;
          job = do_job(c, job, nullptr, nullptr, steps < 64, ql, lane);
        }
      }
      xbar(&c.cnt[48], nb * (++ep));
      ++rounds;
    }
  }

  // ---- phase 5: centre ranks (O(nC^2) LDS-tiled) + row splits ----
  {
    u64* shp = reinterpret_cast<u64*>(listX);     // 8KB alias of the dead list
    const int nC = ald(&c.cnt[4]);
    for (int base = blockIdx.x * NT; base < nC; base += nb * NT) {
      int idx = base + threadIdx.x;
      bool have = idx < nC;
      u64 mykey = have ? ald64(&c.centre_key[idx]) : 0;
      int myv = have ? ald(&c.centre_v[idx]) : 0;
      int myrank = 0;
      for (int cs = 0; cs < nC; cs += NT) {
        int j = cs + threadIdx.x;
        shp[threadIdx.x] = (j < nC) ? ald64(&c.centre_key[j]) : ~0ull;
        __syncthreads();
        int lim = min(NT, nC - cs);
        for (int t = 0; t < lim; ++t) myrank += (shp[t] < mykey) ? 1 : 0;
        __syncthreads();
      }
      if (have) {
        c.out_sel[myrank] = myv;   // host-read only: plain store ok
        ast(&c.rank_of[myv], myrank);
      }
    }
    if (blockIdx.x == 0 && threadIdx.x == 0) {
      int run = 0;
      c.out_rs[0] = 0;
      for (int s = 0; s < c.nseg; ++s) { run += ald(&c.cnt[8 + s]); c.out_rs[s + 1] = run; }
    }
  }
  xbar(&c.cnt[48], nb * (++ep));   // rank_of complete before gather

  // ---- phase 6: ggather ----
  {
    const int gtid = blockIdx.x * NT + threadIdx.x;
    const int nthr = nb * NT;
    for (int v = gtid; v < c.V; v += nthr) {
      u64 y = ald64(&c.assign[v]);
      u64 pv = pack_key(c.hier[v], v);
      int ctr = (y < pv) ? (int)(y & IDX_MASK) : v;   // y>=pv -> centre -> self
      c.out_gg[v] = ald(&c.rank_of[ctr]);
    }
  }
}

extern "C" void kernel_launch(void* const* d_in, const int* in_sizes, int n_in,
                              void* d_out, int out_size, void* d_ws, size_t ws_size,
                              hipStream_t stream) {
  Ctx c;
  c.neighs = (const int*)d_in[0];
  c.hier = (const float*)d_in[1];
  c.row_splits = (const int*)d_in[2];
  c.V = in_sizes[1];
  c.K = in_sizes[0] / c.V;
  c.nseg = in_sizes[2] - 1;

  char* pm = (char*)d_ws;
  const size_t V = (size_t)c.V;
  c.assign = (u64*)pm;        pm += V * 8;   // -> ~0 (alive)
  c.nsmall = (int*)pm;        pm += V * 4;   // -> 0
  c.kmask = (int*)pm;         pm += V * 16;  // fully written in phase 1 (K==96)
  c.centre_key = (u64*)pm;    pm += V * 8;
  c.centre_v = (int*)pm;      pm += V * 4;
  c.rank_of = (int*)pm;       pm += V * 4;
  c.cnt = (int*)pm;           pm += 64 * 4;

  int* out = (int*)d_out;
  c.out_sel = out;
  c.out_rs = out + c.V;
  c.out_gg = out + c.V + c.nseg + 1;

  hipMemsetAsync(d_ws, 0xFF, V * 8, stream);            // assign
  hipMemsetAsync((void*)c.nsmall, 0, V * 4, stream);    // counters
  hipMemsetAsync((void*)c.cnt, 0, 64 * 4, stream);
  hipMemsetAsync((void*)c.out_sel, 0xFF, V * 4, stream);

  void* args[] = { &c };
  hipLaunchCooperativeKernel((void*)k_main, dim3(NBW), dim3(NT), args, 0, stream);
}